// Round 7
// baseline (390.877 us; speedup 1.0000x reference)
//
#include <hip/hip_runtime.h>

typedef float f4v __attribute__((ext_vector_type(4), aligned(4)));
typedef float f2v __attribute__((ext_vector_type(2), aligned(4)));

#define LVAL 2.8853900817779268f  /* 2*log2(e) */
#define C1P 2.8853900817779268f   /* L */
#define C2P -0.6411977959506504f  /* -2L/9 */

__device__ __forceinline__ float rfl(float v) {
  return __int_as_float(__builtin_amdgcn_readfirstlane(__float_as_int(v)));
}
// r = rcp(1+exp2(z));  tanh(v) = 1-2r when z = L*v
__device__ __forceinline__ float rform(float z) {
  float e = __builtin_amdgcn_exp2f(z);
  return __builtin_amdgcn_rcpf(e + 1.0f);
}
// full tanh from pooled r-sum S: tanh(1-(2/9)S)
__device__ __forceinline__ float ptanh(float S) {
  float r = rform(fmaf(C2P, S, C1P));
  return fmaf(-2.0f, r, 1.0f);
}

__global__ __launch_bounds__(256, 4) void smartpixel_kernel(
    const float* __restrict__ x, const float* __restrict__ dww,
    const float* __restrict__ pww, const float* __restrict__ pwb,
    const float* __restrict__ cvw, const float* __restrict__ cvb,
    const float* __restrict__ w1, const float* __restrict__ b1,
    const float* __restrict__ w2, const float* __restrict__ b2,
    const float* __restrict__ w3, const float* __restrict__ b3,
    float* __restrict__ out, int nsamp) {
  const int g = blockIdx.x * 256 + threadIdx.x;
  const int s = g >> 2;   // sample
  const int t = g & 3;    // quad lane: out cols {0-4},{5-8},{9-13},{14-17}
  if (s >= nsamp) return;

  const int cb = (0x0D090500u >> (8 * t)) & 0xFF;  // window col base {0,5,9,13}
  const float* xb = x + (long)s * 546 + cb;
  const bool tOdd = (t & 1) != 0;
  const bool isT1 = (t == 1), isT3 = (t == 3);
  const int hT = t >> 1;

  // depthwise weights raw (uniform -> s_load)
  const float kd0 = dww[0], kd1 = dww[1], kd2 = dww[2], kd3 = dww[3], kd4 = dww[4],
              kd5 = dww[5], kd6 = dww[6], kd7 = dww[7], kd8 = dww[8], kd9 = dww[9],
              kd10 = dww[10], kd11 = dww[11], kd12 = dww[12], kd13 = dww[13],
              kd14 = dww[14], kd15 = dww[15], kd16 = dww[16], kd17 = dww[17];
  // pw stage folded: z_p = zb_p + zp0_p*d0 + zp1_p*d1  (exp2 arg)
  const float zp0 = rfl(LVAL * pww[0]), zp1 = rfl(LVAL * pww[1]),
              zp2 = rfl(LVAL * pww[2]), zp3 = rfl(LVAL * pww[3]),
              zp4 = rfl(LVAL * pww[4]), zp5 = rfl(LVAL * pww[5]),
              zp6 = rfl(LVAL * pww[6]), zp7 = rfl(LVAL * pww[7]),
              zp8 = rfl(LVAL * pww[8]), zp9 = rfl(LVAL * pww[9]);
  const float zb0 = rfl(LVAL * pwb[0]), zb1 = rfl(LVAL * pwb[1]),
              zb2 = rfl(LVAL * pwb[2]), zb3 = rfl(LVAL * pwb[3]),
              zb4 = rfl(LVAL * pwb[4]);
  // cv stage folded onto r: y_q = zcb_q + sum_p zc_qp * r_p  (exp2 arg)
  // zc = -2L*cvw ; zcb = L*(cvb + sum_p cvw)
#define ZC(q, p) rfl(-2.0f * LVAL * cvw[5 * (q) + (p)])
  const float zc0 = ZC(0, 0), zc1 = ZC(0, 1), zc2 = ZC(0, 2), zc3 = ZC(0, 3), zc4 = ZC(0, 4);
  const float zc5 = ZC(1, 0), zc6 = ZC(1, 1), zc7 = ZC(1, 2), zc8 = ZC(1, 3), zc9 = ZC(1, 4);
  const float zc10 = ZC(2, 0), zc11 = ZC(2, 1), zc12 = ZC(2, 2), zc13 = ZC(2, 3), zc14 = ZC(2, 4);
  const float zc15 = ZC(3, 0), zc16 = ZC(3, 1), zc17 = ZC(3, 2), zc18 = ZC(3, 3), zc19 = ZC(3, 4);
  const float zc20 = ZC(4, 0), zc21 = ZC(4, 1), zc22 = ZC(4, 2), zc23 = ZC(4, 3), zc24 = ZC(4, 4);
#define ZCB(q) rfl(LVAL * (cvb[q] + cvw[5 * (q)] + cvw[5 * (q) + 1] + cvw[5 * (q) + 2] + \
                            cvw[5 * (q) + 3] + cvw[5 * (q) + 4]))
  const float zcb0 = ZCB(0), zcb1 = ZCB(1), zcb2 = ZCB(2), zcb3 = ZCB(3), zcb4 = ZCB(4);

  // 3-slot window, 8 cols, 2 channels — all named scalars
#define DECLSLOT(S)                                                          \
  float XA##S##_0, XA##S##_1, XA##S##_2, XA##S##_3, XA##S##_4, XA##S##_5,    \
      XA##S##_6, XA##S##_7, XB##S##_0, XB##S##_1, XB##S##_2, XB##S##_3,      \
      XB##S##_4, XB##S##_5, XB##S##_6, XB##S##_7;
  DECLSLOT(0) DECLSLOT(1) DECLSLOT(2)

#define LDROW(S, PTR)                                                        \
  do {                                                                       \
    const float* p_ = (PTR);                                                 \
    f4v a0_ = *reinterpret_cast<const f4v*>(p_);                             \
    f4v a1_ = *reinterpret_cast<const f4v*>(p_ + 4);                         \
    f4v c0_ = *reinterpret_cast<const f4v*>(p_ + 273);                       \
    f4v c1_ = *reinterpret_cast<const f4v*>(p_ + 277);                       \
    XA##S##_0 = a0_[0]; XA##S##_1 = a0_[1]; XA##S##_2 = a0_[2];              \
    XA##S##_3 = a0_[3]; XA##S##_4 = a1_[0]; XA##S##_5 = a1_[1];              \
    XA##S##_6 = a1_[2]; XA##S##_7 = a1_[3];                                  \
    XB##S##_0 = c0_[0]; XB##S##_1 = c0_[1]; XB##S##_2 = c0_[2];              \
    XB##S##_3 = c0_[3]; XB##S##_4 = c1_[0]; XB##S##_5 = c1_[1];              \
    XB##S##_6 = c1_[2]; XB##S##_7 = c1_[3];                                  \
  } while (0)

  // per-wpos pool accumulators of r-values: 5 channels x 5 positions
  float P0_0 = 0.f, P0_1 = 0.f, P0_2 = 0.f, P0_3 = 0.f, P0_4 = 0.f;
  float P1_0 = 0.f, P1_1 = 0.f, P1_2 = 0.f, P1_3 = 0.f, P1_4 = 0.f;
  float P2_0 = 0.f, P2_1 = 0.f, P2_2 = 0.f, P2_3 = 0.f, P2_4 = 0.f;
  float P3_0 = 0.f, P3_1 = 0.f, P3_2 = 0.f, P3_3 = 0.f, P3_4 = 0.f;
  float P4_0 = 0.f, P4_1 = 0.f, P4_2 = 0.f, P4_3 = 0.f, P4_4 = 0.f;

  float H0 = 0.f, H1 = 0.f, H2 = 0.f, H3 = 0.f, H4 = 0.f, H5 = 0.f, H6 = 0.f,
        H7 = 0.f, H8 = 0.f, H9 = 0.f, H10 = 0.f, H11 = 0.f, H12 = 0.f,
        H13 = 0.f, H14 = 0.f, H15 = 0.f;

#define POS(SA, SB, SC, J0, J1, J2, PP)                                      \
  do {                                                                       \
    float d0 = XA##SA##_##J0 * kd0 + XA##SA##_##J1 * kd1 + XA##SA##_##J2 * kd2 \
             + XA##SB##_##J0 * kd3 + XA##SB##_##J1 * kd4 + XA##SB##_##J2 * kd5 \
             + XA##SC##_##J0 * kd6 + XA##SC##_##J1 * kd7 + XA##SC##_##J2 * kd8; \
    float d1 = XB##SA##_##J0 * kd9 + XB##SA##_##J1 * kd10 + XB##SA##_##J2 * kd11 \
             + XB##SB##_##J0 * kd12 + XB##SB##_##J1 * kd13 + XB##SB##_##J2 * kd14 \
             + XB##SC##_##J0 * kd15 + XB##SC##_##J1 * kd16 + XB##SC##_##J2 * kd17; \
    float r0 = rform(zb0 + zp0 * d0 + zp1 * d1);                             \
    float r1 = rform(zb1 + zp2 * d0 + zp3 * d1);                             \
    float r2 = rform(zb2 + zp4 * d0 + zp5 * d1);                             \
    float r3 = rform(zb3 + zp6 * d0 + zp7 * d1);                             \
    float r4 = rform(zb4 + zp8 * d0 + zp9 * d1);                             \
    P0_##PP += rform(zcb0 + zc0 * r0 + zc1 * r1 + zc2 * r2 + zc3 * r3 + zc4 * r4);     \
    P1_##PP += rform(zcb1 + zc5 * r0 + zc6 * r1 + zc7 * r2 + zc8 * r3 + zc9 * r4);     \
    P2_##PP += rform(zcb2 + zc10 * r0 + zc11 * r1 + zc12 * r2 + zc13 * r3 + zc14 * r4); \
    P3_##PP += rform(zcb3 + zc15 * r0 + zc16 * r1 + zc17 * r2 + zc18 * r3 + zc19 * r4); \
    P4_##PP += rform(zcb4 + zc20 * r0 + zc21 * r1 + zc22 * r2 + zc23 * r3 + zc24 * r4); \
  } while (0)

  // even lanes (t0,t2): wpos 0-4. t1: wpos 0-3. t3: wpos 1-4.
#define ROWBODY(SA, SB, SC)                                                  \
  do {                                                                       \
    if (!isT3) POS(SA, SB, SC, 0, 1, 2, 0);                                  \
    POS(SA, SB, SC, 1, 2, 3, 1);                                             \
    POS(SA, SB, SC, 2, 3, 4, 2);                                             \
    POS(SA, SB, SC, 3, 4, 5, 3);                                             \
    if (!isT1) POS(SA, SB, SC, 4, 5, 6, 4);                                  \
  } while (0)

#define ACCH(O)                                                              \
  {                                                                          \
    f2v wv = *reinterpret_cast<const f2v*>(wb_ + (O) * 90);                  \
    H##O += clo * wv[0] + chi * wv[1];                                       \
  }
#define FCH1(C)                                                              \
  do {                                                                       \
    float sA = P##C##_0 + P##C##_1 + P##C##_2;                               \
    float sMe = P##C##_3 + P##C##_4;                                         \
    float sMo = isT3 ? P##C##_1 : P##C##_0;                                  \
    float myMid = tOdd ? sMo : sMe;                                          \
    float sB = P##C##_2 + P##C##_3 + (isT3 ? P##C##_4 : P##C##_1);           \
    float midFull = myMid + __shfl_xor(myMid, 1, 64);                        \
    float pvA = ptanh(sA);                                                   \
    float sHi = tOdd ? sB : midFull;                                         \
    float chi = ptanh(sHi);                                                  \
    float clo = tOdd ? 0.0f : pvA;                                           \
    const float* wb_ = w1 + (C) * 18 + rr6 + hT * 3 + (tOdd ? 1 : 0);        \
    ACCH(0) ACCH(1) ACCH(2) ACCH(3) ACCH(4) ACCH(5) ACCH(6) ACCH(7)          \
    ACCH(8) ACCH(9) ACCH(10) ACCH(11) ACCH(12) ACCH(13) ACCH(14) ACCH(15)    \
    P##C##_0 = 0.f; P##C##_1 = 0.f; P##C##_2 = 0.f; P##C##_3 = 0.f;          \
    P##C##_4 = 0.f;                                                          \
  } while (0)

  // prologue: rows 0,1
  LDROW(0, xb);
  LDROW(1, xb + 21);

#pragma unroll 1
  for (int rg = 0; rg < 3; ++rg) {
    const float* xr = xb + rg * 63;  // row 3*rg
    const int rr6 = rg * 6;
    LDROW(2, xr + 42);               // row 3rg+2
    ROWBODY(0, 1, 2);                // out row 3rg
    LDROW(0, xr + 63);               // row 3rg+3
    ROWBODY(1, 2, 0);                // out row 3rg+1
    LDROW(1, xr + 84);               // row 3rg+4
    ROWBODY(2, 0, 1);                // out row 3rg+2
    FCH1(0); FCH1(1); FCH1(2); FCH1(3); FCH1(4);
  }

  // quad-reduce fc1; h1 = tanh(H+b1) via r-form (all lanes end with full h1)
#define RED(O)                                                               \
  H##O += __shfl_xor(H##O, 1, 64);                                           \
  H##O += __shfl_xor(H##O, 2, 64);                                           \
  {                                                                          \
    float rr_ = rform((H##O + b1[O]) * LVAL);                                \
    H##O = fmaf(-2.0f, rr_, 1.0f);                                           \
  }
  RED(0) RED(1) RED(2) RED(3) RED(4) RED(5) RED(6) RED(7)
  RED(8) RED(9) RED(10) RED(11) RED(12) RED(13) RED(14) RED(15)

  // fc2 split: this lane computes h2[4t .. 4t+3]
  const int myo = 4 * t;
  float g0, g1, g2, g3;
#define FC2S(I)                                                              \
  {                                                                          \
    const float* wr = w2 + (myo + (I)) * 16;                                 \
    f4v wa = *reinterpret_cast<const f4v*>(wr);                              \
    f4v wb = *reinterpret_cast<const f4v*>(wr + 4);                          \
    f4v wc = *reinterpret_cast<const f4v*>(wr + 8);                          \
    f4v wd = *reinterpret_cast<const f4v*>(wr + 12);                         \
    float acc = b2[myo + (I)]                                                \
        + H0 * wa[0] + H1 * wa[1] + H2 * wa[2] + H3 * wa[3]                  \
        + H4 * wb[0] + H5 * wb[1] + H6 * wb[2] + H7 * wb[3]                  \
        + H8 * wc[0] + H9 * wc[1] + H10 * wc[2] + H11 * wc[3]                \
        + H12 * wd[0] + H13 * wd[1] + H14 * wd[2] + H15 * wd[3];             \
    float rr_ = rform(acc * LVAL);                                           \
    g##I = fmaf(-2.0f, rr_, 1.0f);                                           \
  }
  FC2S(0) FC2S(1) FC2S(2) FC2S(3)

  // gather full h2 across quad: reg (m,i) holds h2[4*(t^m)+i]
#define GATH(I)                                                              \
  float hB_##I = __shfl_xor(g##I, 1, 64);                                    \
  float hC_##I = __shfl_xor(g##I, 2, 64);                                    \
  float hD_##I = __shfl_xor(hB_##I, 2, 64);
  GATH(0) GATH(1) GATH(2) GATH(3)

  // fc3: t0,t1 -> 4 outputs at {0,4}; t2,t3 -> 3 outputs at {8,11}
  const int base = 4 * t - (hT & (t & 1));  // 0,4,8,11
  const float* w3t = w3 + base * 16;
  const int offA = 4 * t, offB = 4 * (t ^ 1), offC = 4 * (t ^ 2), offD = 4 * (t ^ 3);
#define DOT3(OO, ROFF)                                                       \
  float o##OO;                                                               \
  {                                                                          \
    f4v wa = *reinterpret_cast<const f4v*>(w3t + (ROFF) + offA);             \
    f4v wb = *reinterpret_cast<const f4v*>(w3t + (ROFF) + offB);             \
    f4v wc = *reinterpret_cast<const f4v*>(w3t + (ROFF) + offC);             \
    f4v wd = *reinterpret_cast<const f4v*>(w3t + (ROFF) + offD);             \
    o##OO = b3[base + (OO)]                                                  \
        + g0 * wa[0] + g1 * wa[1] + g2 * wa[2] + g3 * wa[3]                  \
        + hB_0 * wb[0] + hB_1 * wb[1] + hB_2 * wb[2] + hB_3 * wb[3]          \
        + hC_0 * wc[0] + hC_1 * wc[1] + hC_2 * wc[2] + hC_3 * wc[3]          \
        + hD_0 * wd[0] + hD_1 * wd[1] + hD_2 * wd[2] + hD_3 * wd[3];         \
  }
  DOT3(0, 0) DOT3(1, 16) DOT3(2, 32)
  float* po = out + (long)s * 14 + base;
  if (t < 2) {
    DOT3(3, 48)
    f4v v; v[0] = o0; v[1] = o1; v[2] = o2; v[3] = o3;
    *reinterpret_cast<f4v*>(po) = v;
  } else if (t == 2) {
    f2v v; v[0] = o0; v[1] = o1;
    *reinterpret_cast<f2v*>(po) = v;
    po[2] = o2;
  } else {
    po[0] = o0;
    f2v v; v[0] = o1; v[1] = o2;
    *reinterpret_cast<f2v*>(po + 1) = v;
  }
}

extern "C" void kernel_launch(void* const* d_in, const int* in_sizes, int n_in,
                              void* d_out, int out_size, void* d_ws, size_t ws_size,
                              hipStream_t stream) {
  const float* x      = (const float*)d_in[0];
  const float* dw_w   = (const float*)d_in[1];
  const float* pw_w   = (const float*)d_in[2];
  const float* pw_b   = (const float*)d_in[3];
  const float* conv_w = (const float*)d_in[4];
  const float* conv_b = (const float*)d_in[5];
  const float* w1     = (const float*)d_in[6];
  const float* b1     = (const float*)d_in[7];
  const float* w2     = (const float*)d_in[8];
  const float* b2     = (const float*)d_in[9];
  const float* w3     = (const float*)d_in[10];
  const float* b3     = (const float*)d_in[11];
  float* out = (float*)d_out;

  int nsamp = in_sizes[0] / 546;
  long nthreads = 4L * nsamp;
  int blocks = (int)((nthreads + 255) / 256);
  smartpixel_kernel<<<blocks, 256, 0, stream>>>(
      x, dw_w, pw_w, pw_b, conv_w, conv_b, w1, b1, w2, b2, w3, b3, out, nsamp);
}

// Round 8
// 133.278 us; speedup vs baseline: 2.9328x; 2.9328x over previous
//
#include <hip/hip_runtime.h>

typedef float f4v __attribute__((ext_vector_type(4), aligned(4)));
typedef float f2v __attribute__((ext_vector_type(2), aligned(4)));

#define LVAL 2.8853900817779268f  /* 2*log2(e) */
#define C1P 2.8853900817779268f   /* L */
#define C2P -0.6411977959506504f  /* -2L/9 */

// r = rcp(1+exp2(z));  tanh(v) = 1-2r when z = L*v
__device__ __forceinline__ float rform(float z) {
  float e = __builtin_amdgcn_exp2f(z);
  return __builtin_amdgcn_rcpf(e + 1.0f);
}
__device__ __forceinline__ float fast_tanh(float x) {
  float r = rform(x * LVAL);
  return fmaf(-2.0f, r, 1.0f);
}
// pooled tanh from r-sum S: tanh(1-(2/9)S)
__device__ __forceinline__ float ptanh(float S) {
  float r = rform(fmaf(C2P, S, C1P));
  return fmaf(-2.0f, r, 1.0f);
}

// prep: fold pw/cv weights into exp2-domain constants in d_ws
// fw[0..9]=L*pww, fw[10..14]=L*pwb, fw[15..39]=-2L*cvw, fw[40..44]=L*(cvb+sum cvw)
__global__ void fold_weights(const float* __restrict__ pww,
                             const float* __restrict__ pwb,
                             const float* __restrict__ cvw,
                             const float* __restrict__ cvb,
                             float* __restrict__ fw) {
  int i = threadIdx.x;
  if (i < 10) {
    fw[i] = LVAL * pww[i];
  } else if (i < 15) {
    fw[i] = LVAL * pwb[i - 10];
  } else if (i < 40) {
    fw[i] = -2.0f * LVAL * cvw[i - 15];
  } else if (i < 45) {
    int q = i - 40;
    float s = cvb[q] + cvw[5 * q] + cvw[5 * q + 1] + cvw[5 * q + 2] +
              cvw[5 * q + 3] + cvw[5 * q + 4];
    fw[i] = LVAL * s;
  }
}

__global__ __launch_bounds__(256, 4) void smartpixel_kernel(
    const float* __restrict__ x, const float* __restrict__ dww,
    const float* __restrict__ fw, const float* __restrict__ w1,
    const float* __restrict__ b1, const float* __restrict__ w2,
    const float* __restrict__ b2, const float* __restrict__ w3,
    const float* __restrict__ b3, float* __restrict__ out, int nsamp) {
  const int g = blockIdx.x * 256 + threadIdx.x;
  const int s = g >> 2;   // sample
  const int t = g & 3;    // quad lane: out cols {0-4},{5-8},{9-13},{14-17}
  if (s >= nsamp) return;

  const int cb = (0x0D090500u >> (8 * t)) & 0xFF;  // window col base {0,5,9,13}
  const float* xb = x + (long)s * 546 + cb;
  const bool tOdd = (t & 1) != 0;
  const bool isT1 = (t == 1), isT3 = (t == 3);
  const int hT = t >> 1;

  // depthwise weights raw (uniform -> s_load)
  const float kd0 = dww[0], kd1 = dww[1], kd2 = dww[2], kd3 = dww[3], kd4 = dww[4],
              kd5 = dww[5], kd6 = dww[6], kd7 = dww[7], kd8 = dww[8], kd9 = dww[9],
              kd10 = dww[10], kd11 = dww[11], kd12 = dww[12], kd13 = dww[13],
              kd14 = dww[14], kd15 = dww[15], kd16 = dww[16], kd17 = dww[17];
  // folded constants (uniform -> s_load from d_ws)
  const float zp0 = fw[0], zp1 = fw[1], zp2 = fw[2], zp3 = fw[3], zp4 = fw[4],
              zp5 = fw[5], zp6 = fw[6], zp7 = fw[7], zp8 = fw[8], zp9 = fw[9];
  const float zb0 = fw[10], zb1 = fw[11], zb2 = fw[12], zb3 = fw[13], zb4 = fw[14];
  const float zc0 = fw[15], zc1 = fw[16], zc2 = fw[17], zc3 = fw[18], zc4 = fw[19],
              zc5 = fw[20], zc6 = fw[21], zc7 = fw[22], zc8 = fw[23], zc9 = fw[24],
              zc10 = fw[25], zc11 = fw[26], zc12 = fw[27], zc13 = fw[28], zc14 = fw[29],
              zc15 = fw[30], zc16 = fw[31], zc17 = fw[32], zc18 = fw[33], zc19 = fw[34],
              zc20 = fw[35], zc21 = fw[36], zc22 = fw[37], zc23 = fw[38], zc24 = fw[39];
  const float zcb0 = fw[40], zcb1 = fw[41], zcb2 = fw[42], zcb3 = fw[43], zcb4 = fw[44];

  // 3-slot window, 8 cols, 2 channels — all named scalars
#define DECLSLOT(S)                                                          \
  float XA##S##_0, XA##S##_1, XA##S##_2, XA##S##_3, XA##S##_4, XA##S##_5,    \
      XA##S##_6, XA##S##_7, XB##S##_0, XB##S##_1, XB##S##_2, XB##S##_3,      \
      XB##S##_4, XB##S##_5, XB##S##_6, XB##S##_7;
  DECLSLOT(0) DECLSLOT(1) DECLSLOT(2)

#define LDROW(S, PTR)                                                        \
  do {                                                                       \
    const float* p_ = (PTR);                                                 \
    f4v a0_ = *reinterpret_cast<const f4v*>(p_);                             \
    f4v a1_ = *reinterpret_cast<const f4v*>(p_ + 4);                         \
    f4v c0_ = *reinterpret_cast<const f4v*>(p_ + 273);                       \
    f4v c1_ = *reinterpret_cast<const f4v*>(p_ + 277);                       \
    XA##S##_0 = a0_[0]; XA##S##_1 = a0_[1]; XA##S##_2 = a0_[2];              \
    XA##S##_3 = a0_[3]; XA##S##_4 = a1_[0]; XA##S##_5 = a1_[1];              \
    XA##S##_6 = a1_[2]; XA##S##_7 = a1_[3];                                  \
    XB##S##_0 = c0_[0]; XB##S##_1 = c0_[1]; XB##S##_2 = c0_[2];              \
    XB##S##_3 = c0_[3]; XB##S##_4 = c1_[0]; XB##S##_5 = c1_[1];              \
    XB##S##_6 = c1_[2]; XB##S##_7 = c1_[3];                                  \
  } while (0)

  // per-wpos pool accumulators of r-values: 5 channels x 5 positions
  float P0_0 = 0.f, P0_1 = 0.f, P0_2 = 0.f, P0_3 = 0.f, P0_4 = 0.f;
  float P1_0 = 0.f, P1_1 = 0.f, P1_2 = 0.f, P1_3 = 0.f, P1_4 = 0.f;
  float P2_0 = 0.f, P2_1 = 0.f, P2_2 = 0.f, P2_3 = 0.f, P2_4 = 0.f;
  float P3_0 = 0.f, P3_1 = 0.f, P3_2 = 0.f, P3_3 = 0.f, P3_4 = 0.f;
  float P4_0 = 0.f, P4_1 = 0.f, P4_2 = 0.f, P4_3 = 0.f, P4_4 = 0.f;

  float H0 = 0.f, H1 = 0.f, H2 = 0.f, H3 = 0.f, H4 = 0.f, H5 = 0.f, H6 = 0.f,
        H7 = 0.f, H8 = 0.f, H9 = 0.f, H10 = 0.f, H11 = 0.f, H12 = 0.f,
        H13 = 0.f, H14 = 0.f, H15 = 0.f;

#define POS(SA, SB, SC, J0, J1, J2, PP)                                      \
  do {                                                                       \
    float d0 = XA##SA##_##J0 * kd0 + XA##SA##_##J1 * kd1 + XA##SA##_##J2 * kd2 \
             + XA##SB##_##J0 * kd3 + XA##SB##_##J1 * kd4 + XA##SB##_##J2 * kd5 \
             + XA##SC##_##J0 * kd6 + XA##SC##_##J1 * kd7 + XA##SC##_##J2 * kd8; \
    float d1 = XB##SA##_##J0 * kd9 + XB##SA##_##J1 * kd10 + XB##SA##_##J2 * kd11 \
             + XB##SB##_##J0 * kd12 + XB##SB##_##J1 * kd13 + XB##SB##_##J2 * kd14 \
             + XB##SC##_##J0 * kd15 + XB##SC##_##J1 * kd16 + XB##SC##_##J2 * kd17; \
    float r0 = rform(zb0 + zp0 * d0 + zp1 * d1);                             \
    float r1 = rform(zb1 + zp2 * d0 + zp3 * d1);                             \
    float r2 = rform(zb2 + zp4 * d0 + zp5 * d1);                             \
    float r3 = rform(zb3 + zp6 * d0 + zp7 * d1);                             \
    float r4 = rform(zb4 + zp8 * d0 + zp9 * d1);                             \
    P0_##PP += rform(zcb0 + zc0 * r0 + zc1 * r1 + zc2 * r2 + zc3 * r3 + zc4 * r4);     \
    P1_##PP += rform(zcb1 + zc5 * r0 + zc6 * r1 + zc7 * r2 + zc8 * r3 + zc9 * r4);     \
    P2_##PP += rform(zcb2 + zc10 * r0 + zc11 * r1 + zc12 * r2 + zc13 * r3 + zc14 * r4); \
    P3_##PP += rform(zcb3 + zc15 * r0 + zc16 * r1 + zc17 * r2 + zc18 * r3 + zc19 * r4); \
    P4_##PP += rform(zcb4 + zc20 * r0 + zc21 * r1 + zc22 * r2 + zc23 * r3 + zc24 * r4); \
  } while (0)

  // even lanes (t0,t2): wpos 0-4. t1: wpos 0-3. t3: wpos 1-4.
#define ROWBODY(SA, SB, SC)                                                  \
  do {                                                                       \
    if (!isT3) POS(SA, SB, SC, 0, 1, 2, 0);                                  \
    POS(SA, SB, SC, 1, 2, 3, 1);                                             \
    POS(SA, SB, SC, 2, 3, 4, 2);                                             \
    POS(SA, SB, SC, 3, 4, 5, 3);                                             \
    if (!isT1) POS(SA, SB, SC, 4, 5, 6, 4);                                  \
  } while (0)

#define ACCH(O)                                                              \
  {                                                                          \
    f2v wv = *reinterpret_cast<const f2v*>(wb_ + (O) * 90);                  \
    H##O += clo * wv[0] + chi * wv[1];                                       \
  }
#define FCH1(C)                                                              \
  do {                                                                       \
    float sA = P##C##_0 + P##C##_1 + P##C##_2;                               \
    float sMe = P##C##_3 + P##C##_4;                                         \
    float sMo = isT3 ? P##C##_1 : P##C##_0;                                  \
    float myMid = tOdd ? sMo : sMe;                                          \
    float sB = P##C##_2 + P##C##_3 + (isT3 ? P##C##_4 : P##C##_1);           \
    float midFull = myMid + __shfl_xor(myMid, 1, 64);                        \
    float pvA = ptanh(sA);                                                   \
    float sHi = tOdd ? sB : midFull;                                         \
    float chi = ptanh(sHi);                                                  \
    float clo = tOdd ? 0.0f : pvA;                                           \
    const float* wb_ = w1 + (C) * 18 + rr6 + hT * 3 + (tOdd ? 1 : 0);        \
    ACCH(0) ACCH(1) ACCH(2) ACCH(3) ACCH(4) ACCH(5) ACCH(6) ACCH(7)          \
    ACCH(8) ACCH(9) ACCH(10) ACCH(11) ACCH(12) ACCH(13) ACCH(14) ACCH(15)    \
    P##C##_0 = 0.f; P##C##_1 = 0.f; P##C##_2 = 0.f; P##C##_3 = 0.f;          \
    P##C##_4 = 0.f;                                                          \
  } while (0)

  // prologue: rows 0,1
  LDROW(0, xb);
  LDROW(1, xb + 21);

#pragma unroll 1
  for (int rg = 0; rg < 3; ++rg) {
    const float* xr = xb + rg * 63;  // row 3*rg
    const int rr6 = rg * 6;
    LDROW(2, xr + 42);               // row 3rg+2
    ROWBODY(0, 1, 2);                // out row 3rg
    LDROW(0, xr + 63);               // row 3rg+3
    ROWBODY(1, 2, 0);                // out row 3rg+1
    LDROW(1, xr + 84);               // row 3rg+4
    ROWBODY(2, 0, 1);                // out row 3rg+2
    FCH1(0); FCH1(1); FCH1(2); FCH1(3); FCH1(4);
  }

  // quad-reduce fc1, add bias, tanh (all lanes end with full h1)
#define RED(O)                                                               \
  H##O += __shfl_xor(H##O, 1, 64);                                           \
  H##O += __shfl_xor(H##O, 2, 64);                                           \
  H##O = fast_tanh(H##O + b1[O]);
  RED(0) RED(1) RED(2) RED(3) RED(4) RED(5) RED(6) RED(7)
  RED(8) RED(9) RED(10) RED(11) RED(12) RED(13) RED(14) RED(15)

  // fc2 redundant per lane (uniform weights -> s_loads)
#define FC2(O)                                                               \
  float q##O = fast_tanh(b2[(O)]                                             \
      + H0 * w2[(O) * 16 + 0] + H1 * w2[(O) * 16 + 1] + H2 * w2[(O) * 16 + 2]\
      + H3 * w2[(O) * 16 + 3] + H4 * w2[(O) * 16 + 4] + H5 * w2[(O) * 16 + 5]\
      + H6 * w2[(O) * 16 + 6] + H7 * w2[(O) * 16 + 7] + H8 * w2[(O) * 16 + 8]\
      + H9 * w2[(O) * 16 + 9] + H10 * w2[(O) * 16 + 10]                      \
      + H11 * w2[(O) * 16 + 11] + H12 * w2[(O) * 16 + 12]                    \
      + H13 * w2[(O) * 16 + 13] + H14 * w2[(O) * 16 + 14]                    \
      + H15 * w2[(O) * 16 + 15]);
  FC2(0) FC2(1) FC2(2) FC2(3) FC2(4) FC2(5) FC2(6) FC2(7)
  FC2(8) FC2(9) FC2(10) FC2(11) FC2(12) FC2(13) FC2(14) FC2(15)

  // fc3: t0,t1 -> 4 outputs at {0,4}; t2,t3 -> 3 outputs at {8,11}
  const int base = 4 * t - (hT & (t & 1));  // 0,4,8,11
  const float* w3t = w3 + base * 16;
#define DOT3(OO, ROFF)                                                       \
  float o##OO;                                                               \
  {                                                                          \
    f4v wa = *reinterpret_cast<const f4v*>(w3t + (ROFF) + 0);                \
    f4v wb = *reinterpret_cast<const f4v*>(w3t + (ROFF) + 4);                \
    f4v wc = *reinterpret_cast<const f4v*>(w3t + (ROFF) + 8);                \
    f4v wd = *reinterpret_cast<const f4v*>(w3t + (ROFF) + 12);               \
    o##OO = b3[base + (OO)]                                                  \
        + q0 * wa[0] + q1 * wa[1] + q2 * wa[2] + q3 * wa[3]                  \
        + q4 * wb[0] + q5 * wb[1] + q6 * wb[2] + q7 * wb[3]                  \
        + q8 * wc[0] + q9 * wc[1] + q10 * wc[2] + q11 * wc[3]                \
        + q12 * wd[0] + q13 * wd[1] + q14 * wd[2] + q15 * wd[3];             \
  }
  DOT3(0, 0) DOT3(1, 16) DOT3(2, 32)
  float* po = out + (long)s * 14 + base;
  if (t < 2) {
    DOT3(3, 48)
    f4v v; v[0] = o0; v[1] = o1; v[2] = o2; v[3] = o3;
    *reinterpret_cast<f4v*>(po) = v;
  } else if (t == 2) {
    f2v v; v[0] = o0; v[1] = o1;
    *reinterpret_cast<f2v*>(po) = v;
    po[2] = o2;
  } else {
    po[0] = o0;
    f2v v; v[0] = o1; v[1] = o2;
    *reinterpret_cast<f2v*>(po + 1) = v;
  }
}

extern "C" void kernel_launch(void* const* d_in, const int* in_sizes, int n_in,
                              void* d_out, int out_size, void* d_ws, size_t ws_size,
                              hipStream_t stream) {
  const float* x      = (const float*)d_in[0];
  const float* dw_w   = (const float*)d_in[1];
  const float* pw_w   = (const float*)d_in[2];
  const float* pw_b   = (const float*)d_in[3];
  const float* conv_w = (const float*)d_in[4];
  const float* conv_b = (const float*)d_in[5];
  const float* w1     = (const float*)d_in[6];
  const float* b1     = (const float*)d_in[7];
  const float* w2     = (const float*)d_in[8];
  const float* b2     = (const float*)d_in[9];
  const float* w3     = (const float*)d_in[10];
  const float* b3     = (const float*)d_in[11];
  float* out = (float*)d_out;
  float* fw = (float*)d_ws;

  fold_weights<<<1, 64, 0, stream>>>(pw_w, pw_b, conv_w, conv_b, fw);

  int nsamp = in_sizes[0] / 546;
  long nthreads = 4L * nsamp;
  int blocks = (int)((nthreads + 255) / 256);
  smartpixel_kernel<<<blocks, 256, 0, stream>>>(
      x, dw_w, fw, w1, b1, w2, b2, w3, b3, out, nsamp);
}